// Round 6
// baseline (53.490 us; speedup 1.0000x reference)
//
#include <hip/hip_runtime.h>

// XORNet SNN: x(T,B,2) -> spikes(T,B,2), Leaky(beta=0.9, thr=1, subtract-reset)
// Thread holds membrane state in registers, walks T sequentially.
// 2 elements/thread => 16B/lane loads/stores.
//
// R4: nt stores -> WRITE 198->168MB (ideal), dur 72.9->50.6us. FETCH stuck
// at 84MB: nt only disables L2 alloc; the MALL/L3 still allocates the write
// stream, evicting ~half of x between graph replays (256-168=88 ~= 84 MB).
// R5: prefetch depth-6 neutral (compiler already scheduled loads; VGPR
// unchanged at 40) -> reverted.
// R6: single change — store via inline asm `global_store_dwordx4 .. nt sc1`
// (nt+sc1 = stream/no-allocate policy at MALL on CDNA). If honored, x stays
// fully L3-resident across replays and FETCH -> ~0.

constexpr int   T    = 20;
constexpr float BETA = 0.9f;
constexpr float THR  = 1.0f;

typedef float f32x4 __attribute__((ext_vector_type(4)));

__global__ __launch_bounds__(256) void snn_xornet_kernel(
    const float* __restrict__ x,
    const float* __restrict__ W1,   // (4,2) row-major
    const float* __restrict__ W2,   // (2,4) row-major
    float* __restrict__ out,
    int nPairs)                     // B/2
{
    const int tid = blockIdx.x * blockDim.x + threadIdx.x;
    if (tid >= nPairs) return;

    // Weights: wave-uniform -> scalar loads (SGPRs); 16 floats, one-time.
    float w1[4][2], w2[2][4];
    #pragma unroll
    for (int o = 0; o < 4; ++o) {
        w1[o][0] = W1[o * 2 + 0];
        w1[o][1] = W1[o * 2 + 1];
    }
    #pragma unroll
    for (int o = 0; o < 2; ++o)
        #pragma unroll
        for (int i = 0; i < 4; ++i)
            w2[o][i] = W2[o * 4 + i];

    // Per-element state (2 batch elements/thread), register-resident.
    float m1[2][4] = {}, s1[2][4] = {};
    float m2[2][2] = {}, s2[2][2] = {};

    const f32x4* __restrict__ xp = reinterpret_cast<const f32x4*>(x) + tid;
    f32x4* __restrict__       op = reinterpret_cast<f32x4*>(out) + tid;
    const size_t strideT = (size_t)nPairs;  // one t-slice in f32x4 units

    #pragma unroll
    for (int t = 0; t < T; ++t) {
        const f32x4 xv = xp[t * strideT];
        const float xin[2][2] = {{xv.x, xv.y}, {xv.z, xv.w}};
        float so[2][2];

        #pragma unroll
        for (int e = 0; e < 2; ++e) {
            // layer 1: cur1 = x @ W1^T ; leaky integrate + subtract reset
            #pragma unroll
            for (int o = 0; o < 4; ++o) {
                const float cur1 = xin[e][0] * w1[o][0] + xin[e][1] * w1[o][1];
                m1[e][o] = BETA * m1[e][o] + cur1 - s1[e][o] * THR;
                s1[e][o] = (m1[e][o] > THR) ? 1.0f : 0.0f;
            }
            // layer 2: cur2 = s1 @ W2^T
            #pragma unroll
            for (int o = 0; o < 2; ++o) {
                float cur2 = s1[e][0] * w2[o][0];
                #pragma unroll
                for (int i = 1; i < 4; ++i) cur2 += s1[e][i] * w2[o][i];
                m2[e][o] = BETA * m2[e][o] + cur2 - s2[e][o] * THR;
                s2[e][o] = (m2[e][o] > THR) ? 1.0f : 0.0f;
                so[e][o] = s2[e][o];
            }
        }

        f32x4 ov;
        ov.x = so[0][0]; ov.y = so[0][1];
        ov.z = so[1][0]; ov.w = so[1][1];
        // nt+sc1 store: write-once output, request stream/no-allocate at
        // every cache level so the write stream stops evicting x from L3.
        f32x4* dst = &op[t * strideT];
        asm volatile("global_store_dwordx4 %0, %1, off nt sc1"
                     :: "v"(dst), "v"(ov) : "memory");
    }
}

extern "C" void kernel_launch(void* const* d_in, const int* in_sizes, int n_in,
                              void* d_out, int out_size, void* d_ws, size_t ws_size,
                              hipStream_t stream) {
    const float* x  = (const float*)d_in[0];
    const float* W1 = (const float*)d_in[1];
    const float* W2 = (const float*)d_in[2];
    float* out = (float*)d_out;

    const int B = in_sizes[0] / (T * 2);   // x is (T,B,2)
    const int nPairs = B / 2;              // 2 batch elements per thread

    const int block = 256;
    const int grid  = (nPairs + block - 1) / block;
    snn_xornet_kernel<<<grid, block, 0, stream>>>(x, W1, W2, out, nPairs);
}

// Round 7
// 50.687 us; speedup vs baseline: 1.0553x; 1.0553x over previous
//
#include <hip/hip_runtime.h>

// XORNet SNN: x(T,B,2) -> spikes(T,B,2), Leaky(beta=0.9, thr=1, subtract-reset)
// Thread holds membrane state in registers, walks T sequentially.
// 2 elements/thread => 16B/lane loads/stores, builtin nt stores.
//
// R4: nt stores -> WRITE ideal (168MB), dur 50.6us. R5: deeper prefetch
// neutral (compiler already schedules). R6: nt+sc1 asm store -> FETCH
// unchanged (L3 is a memory-side cache; ISA bits can't stop write alloc);
// 84MB re-read of x per replay is structural. Best = R4 @ 4.98 TB/s eff.
// R7 theory: fine-grained read<->write alternation pays DRAM turnaround
// (tWTR/tRTW) every iteration. Group T into 4x5: burst-load 5 quads,
// compute, burst-store 5 quads => 5x longer bursts, 5x fewer turnarounds.

constexpr int   T    = 20;
constexpr int   G    = 5;     // t-steps per burst group
constexpr float BETA = 0.9f;
constexpr float THR  = 1.0f;

typedef float f32x4 __attribute__((ext_vector_type(4)));

__global__ __launch_bounds__(256) void snn_xornet_kernel(
    const float* __restrict__ x,
    const float* __restrict__ W1,   // (4,2) row-major
    const float* __restrict__ W2,   // (2,4) row-major
    float* __restrict__ out,
    int nPairs)                     // B/2
{
    const int tid = blockIdx.x * blockDim.x + threadIdx.x;
    if (tid >= nPairs) return;

    // Weights: wave-uniform -> scalar loads (SGPRs); 16 floats, one-time.
    float w1[4][2], w2[2][4];
    #pragma unroll
    for (int o = 0; o < 4; ++o) {
        w1[o][0] = W1[o * 2 + 0];
        w1[o][1] = W1[o * 2 + 1];
    }
    #pragma unroll
    for (int o = 0; o < 2; ++o)
        #pragma unroll
        for (int i = 0; i < 4; ++i)
            w2[o][i] = W2[o * 4 + i];

    // Per-element state (2 batch elements/thread), register-resident.
    float m1[2][4] = {}, s1[2][4] = {};
    float m2[2][2] = {}, s2[2][2] = {};

    const f32x4* __restrict__ xp = reinterpret_cast<const f32x4*>(x) + tid;
    f32x4* __restrict__       op = reinterpret_cast<f32x4*>(out) + tid;
    const size_t strideT = (size_t)nPairs;  // one t-slice in f32x4 units

    #pragma unroll
    for (int g = 0; g < T / G; ++g) {
        // ---- burst read: G quads (all indices compile-time) ----
        f32x4 xv[G];
        #pragma unroll
        for (int k = 0; k < G; ++k)
            xv[k] = xp[(g * G + k) * strideT];

        // ---- compute G steps, hold outputs in registers ----
        f32x4 ov[G];
        #pragma unroll
        for (int k = 0; k < G; ++k) {
            const float xin[2][2] = {{xv[k].x, xv[k].y}, {xv[k].z, xv[k].w}};

            #pragma unroll
            for (int e = 0; e < 2; ++e) {
                // layer 1: cur1 = x @ W1^T ; leaky integrate + subtract reset
                #pragma unroll
                for (int o = 0; o < 4; ++o) {
                    const float cur1 = xin[e][0] * w1[o][0] + xin[e][1] * w1[o][1];
                    m1[e][o] = BETA * m1[e][o] + cur1 - s1[e][o] * THR;
                    s1[e][o] = (m1[e][o] > THR) ? 1.0f : 0.0f;
                }
                // layer 2: cur2 = s1 @ W2^T
                #pragma unroll
                for (int o = 0; o < 2; ++o) {
                    float cur2 = s1[e][0] * w2[o][0];
                    #pragma unroll
                    for (int i = 1; i < 4; ++i) cur2 += s1[e][i] * w2[o][i];
                    m2[e][o] = BETA * m2[e][o] + cur2 - s2[e][o] * THR;
                    s2[e][o] = (m2[e][o] > THR) ? 1.0f : 0.0f;
                }
            }
            ov[k].x = s2[0][0]; ov[k].y = s2[0][1];
            ov[k].z = s2[1][0]; ov[k].w = s2[1][1];
        }

        // ---- burst write: G quads, non-temporal ----
        #pragma unroll
        for (int k = 0; k < G; ++k)
            __builtin_nontemporal_store(ov[k], &op[(g * G + k) * strideT]);
    }
}

extern "C" void kernel_launch(void* const* d_in, const int* in_sizes, int n_in,
                              void* d_out, int out_size, void* d_ws, size_t ws_size,
                              hipStream_t stream) {
    const float* x  = (const float*)d_in[0];
    const float* W1 = (const float*)d_in[1];
    const float* W2 = (const float*)d_in[2];
    float* out = (float*)d_out;

    const int B = in_sizes[0] / (T * 2);   // x is (T,B,2)
    const int nPairs = B / 2;              // 2 batch elements per thread

    const int block = 256;
    const int grid  = (nPairs + block - 1) / block;
    snn_xornet_kernel<<<grid, block, 0, stream>>>(x, W1, W2, out, nPairs);
}